// Round 13
// baseline (223.016 us; speedup 1.0000x reference)
//
#include <hip/hip_runtime.h>
#include <hip/hip_bf16.h>

typedef __attribute__((ext_vector_type(8))) short s16x8;
typedef __attribute__((ext_vector_type(4))) short s16x4;
typedef __attribute__((ext_vector_type(4))) int   i32x4;
typedef __attribute__((ext_vector_type(4))) float f32x4;
typedef __attribute__((ext_vector_type(8))) __bf16 bf16x8;
typedef __attribute__((ext_vector_type(4))) __bf16 bf16x4;

__device__ __forceinline__ short f2bf(float f) {
  unsigned u = __builtin_bit_cast(unsigned, f);
  u = (u + 0x7FFFu + ((u >> 16) & 1u)) >> 16;
  return (short)u;
}
__device__ __forceinline__ float bf2f(short s) {
  unsigned u = ((unsigned)(unsigned short)s) << 16;
  return __builtin_bit_cast(float, u);
}
__device__ __forceinline__ f32x4 mfma16(s16x8 a, s16x8 b, f32x4 c) {
  return __builtin_amdgcn_mfma_f32_16x16x32_bf16(
      __builtin_bit_cast(bf16x8, a), __builtin_bit_cast(bf16x8, b), c, 0, 0, 0);
}
__device__ __forceinline__ void gload16(const void* g, void* l) {
  __builtin_amdgcn_global_load_lds(
      (const __attribute__((address_space(1))) void*)g,
      (__attribute__((address_space(3))) void*)l, 16, 0, 0);
}

// ---------------- merged prep: convert x, bias concat, 6x weight conv+transpose ----
__global__ __launch_bounds__(256) void prep_kernel(
    const float* __restrict__ x, short* __restrict__ xb,
    const float* __restrict__ bq, const float* __restrict__ bk,
    const float* __restrict__ bv, float* __restrict__ bqkv,
    const float* __restrict__ Wq, const float* __restrict__ Wk,
    const float* __restrict__ Wv, const float* __restrict__ Wo,
    const float* __restrict__ W1, const float* __restrict__ W2,
    short* __restrict__ wqkv_t, short* __restrict__ wo_t,
    short* __restrict__ w1_t, short* __restrict__ w2_t) {
  __shared__ float t[32][33];
  const int b = blockIdx.x, tid = threadIdx.x;
  if (b < 1536) {
    int i = b * 256 + tid;
    float4 v0 = ((const float4*)x)[i * 2];
    float4 v1 = ((const float4*)x)[i * 2 + 1];
    s16x8 o;
    o[0] = f2bf(v0.x); o[1] = f2bf(v0.y); o[2] = f2bf(v0.z); o[3] = f2bf(v0.w);
    o[4] = f2bf(v1.x); o[5] = f2bf(v1.y); o[6] = f2bf(v1.z); o[7] = f2bf(v1.w);
    *(s16x8*)&xb[i * 8] = o;
    return;
  }
  if (b < 1545) {
    int i = (b - 1536) * 256 + tid;
    if (i < 2304) bqkv[i] = i < 768 ? bq[i] : (i < 1536 ? bk[i - 768] : bv[i - 1536]);
    return;
  }
  const float* src; short* dst; int K, N, bx, by;
  if (b < 3849) {
    int t4 = b - 1545, wi = t4 / 576, r = t4 % 576;
    bx = r % 24; by = r / 24; K = 768; N = 768;
    src = wi == 0 ? Wq : wi == 1 ? Wk : wi == 2 ? Wv : Wo;
    dst = wi == 0 ? wqkv_t : wi == 1 ? wqkv_t + 768 * 768
        : wi == 2 ? wqkv_t + 2 * 768 * 768 : wo_t;
  } else if (b < 6153) {
    int r = b - 3849; bx = r % 96; by = r / 96; K = 768; N = 3072; src = W1; dst = w1_t;
  } else {
    int r = b - 6153; bx = r % 24; by = r / 24; K = 3072; N = 768; src = W2; dst = w2_t;
  }
  int n0 = bx * 32, k0 = by * 32;
  int tx = tid & 31, ty = tid >> 5;
#pragma unroll
  for (int r = 0; r < 4; ++r) t[ty + r * 8][tx] = src[(long)(k0 + ty + r * 8) * N + n0 + tx];
  __syncthreads();
#pragma unroll
  for (int r = 0; r < 4; ++r)
    dst[(long)(n0 + ty + r * 8) * K + k0 + tx] = f2bf(t[tx][ty + r * 8]);
}

// ---------------- GEMM (3-stage pipeline, round-11 proven schedule) ----------------
// C = A[M][Kfull](cols koff..) @ Bt^T + bias
// OUT_MODE: 0 = bf16 out, 1 = f32 out, 2 = bf16 out with GELU,
//           3 = bf16 SPLIT-K PARTIAL out (plane z at z*M*N; bias on z==0)
template <int OUT_MODE>
__global__ __launch_bounds__(256) void gemm_kernel(const short* __restrict__ A,
                                                   const short* __restrict__ Bt,
                                                   const float* __restrict__ bias,
                                                   void* __restrict__ Cout,
                                                   short* __restrict__ vtout,
                                                   int M, int N, int Kfull, int Ksub) {
  __shared__ short As[3][64 * 64];
  __shared__ short Bs[3][64 * 64];
  const int tid = threadIdx.x;
  const int wave = tid >> 6, lane = tid & 63;
  const int lr = lane & 15, lg = lane >> 4;
  const int wm = wave >> 1, wn = wave & 1;
  const int bm = blockIdx.x, bn = blockIdx.y;
  const long koff = (long)blockIdx.z * Ksub;

  f32x4 acc[4][4] = {};

  const short* Ab = A + (long)bm * 128 * Kfull + koff;
  const short* Bb = Bt + (long)bn * 128 * Kfull + koff;

  int sj[2], sr[2], skc[2];
#pragma unroll
  for (int rnd = 0; rnd < 2; ++rnd) {
    int c = tid + rnd * 256;
    int j = c >> 3, c7 = c & 7;
    int u = c7 ^ (j & 7);
    sj[rnd] = c;
    sr[rnd] = j + ((u >> 2) << 6);
    skc[rnd] = (u & 3) * 8;
  }

  auto STAGE = [&](int buf, int k0) {
#pragma unroll
    for (int rnd = 0; rnd < 2; ++rnd) {
      gload16(Ab + (long)sr[rnd] * Kfull + k0 + skc[rnd], &As[buf][sj[rnd] * 8]);
      gload16(Bb + (long)sr[rnd] * Kfull + k0 + skc[rnd], &Bs[buf][sj[rnd] * 8]);
    }
  };
  auto COMPUTE = [&](int buf) {
    s16x8 af[4], bfr[4];
#pragma unroll
    for (int m = 0; m < 4; ++m) {
      int j = m * 16 + lr;
      int c7 = ((wm << 2) | lg) ^ (lr & 7);
      af[m] = *(const s16x8*)&As[buf][j * 64 + c7 * 8];
    }
#pragma unroll
    for (int n = 0; n < 4; ++n) {
      int j = n * 16 + lr;
      int c7 = ((wn << 2) | lg) ^ (lr & 7);
      bfr[n] = *(const s16x8*)&Bs[buf][j * 64 + c7 * 8];
    }
#pragma unroll
    for (int m = 0; m < 4; ++m)
#pragma unroll
      for (int n = 0; n < 4; ++n)
        acc[m][n] = mfma16(af[m], bfr[n], acc[m][n]);
  };

  const int nt = Ksub >> 5;  // >= 12 for all our shapes
  STAGE(0, 0);
  STAGE(1, 32);
  int cur = 0;
  for (int t = 0; t < nt - 2; ++t) {
    int nb = cur + 2; if (nb >= 3) nb -= 3;
    STAGE(nb, (t + 2) * 32);                 // tile t+2 in flight
    asm volatile("s_waitcnt vmcnt(8)" ::: "memory");  // tile t landed
    __builtin_amdgcn_s_barrier();
    __builtin_amdgcn_sched_barrier(0);
    COMPUTE(cur);
    __builtin_amdgcn_s_barrier();            // all waves done reading buf[cur]
    cur = (cur == 2) ? 0 : cur + 1;
  }
  asm volatile("s_waitcnt vmcnt(4)" ::: "memory");    // tile nt-2 landed
  __builtin_amdgcn_s_barrier();
  __builtin_amdgcn_sched_barrier(0);
  COMPUTE(cur);
  __builtin_amdgcn_s_barrier();
  cur = (cur == 2) ? 0 : cur + 1;
  asm volatile("s_waitcnt vmcnt(0)" ::: "memory");    // tile nt-1 landed
  __builtin_amdgcn_s_barrier();
  __builtin_amdgcn_sched_barrier(0);
  COMPUTE(cur);

  const int gr0 = bm * 128 + wm * 64 + lg * 4;
  const int gc0 = bn * 128 + wn * 64 + lr;
  if (OUT_MODE == 0 && vtout != nullptr && bn >= 12) {
#pragma unroll
    for (int n = 0; n < 4; ++n) {
      int col = gc0 + n * 16;
      float bb = bias[col];
#pragma unroll
      for (int m = 0; m < 4; ++m) {
        s16x4 pk;
#pragma unroll
        for (int j = 0; j < 4; ++j) pk[j] = f2bf(acc[m][n][j] + bb);
        *(s16x4*)&vtout[(long)(col - 1536) * 4096 + gr0 + m * 16] = pk;
      }
    }
    return;
  }
  float* outF = (float*)Cout + (long)blockIdx.z * M * N;
  short* outB = (short*)Cout + (long)blockIdx.z * M * N;
#pragma unroll
  for (int n = 0; n < 4; ++n) {
    int col = gc0 + n * 16;
    float bb = (OUT_MODE == 1 || OUT_MODE == 3)
                   ? ((blockIdx.z == 0) ? bias[col] : 0.f) : bias[col];
#pragma unroll
    for (int m = 0; m < 4; ++m) {
#pragma unroll
      for (int j = 0; j < 4; ++j) {
        int row = gr0 + m * 16 + j;
        float v = acc[m][n][j] + bb;
        if (OUT_MODE == 2) v = 0.5f * v * (1.0f + erff(v * 0.70710678118f));
        if (OUT_MODE == 1)      outF[(long)row * N + col] = v;
        else if (OUT_MODE == 3) outB[(long)row * N + col] = f2bf(v);
        else                    ((short*)Cout)[(long)row * N + col] = f2bf(v);
      }
    }
  }
}

// ---------------- Flash attention v9 (proven): gload_lds K/V staging, bf16 Opart ----
__global__ __launch_bounds__(256) void flash_kernel(const short* __restrict__ qkv,
                                                    const short* __restrict__ vt,
                                                    short* __restrict__ Opart,
                                                    float* __restrict__ Lpart) {
  __shared__ short Kt[2][64 * 64];
  __shared__ short Vs[2][64 * 64];
  __shared__ short Ps[128 * 72];  // [q][kv] padded; also reused for Q staging
  const int tid = threadIdx.x;
  const int wave = tid >> 6, lane = tid & 63;
  const int lr = lane & 15, lg = lane >> 4;
  const int lb = blockIdx.x + 32 * blockIdx.y + 384 * blockIdx.z;
  const int nlb = (lb & 7) * 96 + (lb >> 3);
  const int qb = nlb & 31;
  const int h = (nlb >> 5) % 12;
  const int sp = nlb / 384;
  const int qc = h * 64;
  const int hc = 768 + h * 64;
  const int vr = h * 64;
  const float QSCALE = 0.125f * 1.44269504088896f;
  const int sbase = sp * 2048;

  auto STAGE = [&](int buf, int it) {
    const int s0 = sbase + it * 64;
#pragma unroll
    for (int i = 0; i < 2; ++i) {
      int c = tid + i * 256, row = c >> 3, ch = (c & 7) ^ (row & 7);
      gload16(&qkv[(long)(s0 + row) * 2304 + hc + ch * 8], &Kt[buf][c * 8]);
      gload16(&vt[(long)(vr + row) * 4096 + s0 + ch * 8], &Vs[buf][c * 8]);
    }
  };

  STAGE(0, 0);

#pragma unroll
  for (int i = 0; i < 4; ++i) {
    int c = tid + i * 256;
    int row = c >> 3, cq = (c & 7) * 8;
    *(i32x4*)&Ps[row * 72 + cq] =
        *(const i32x4*)&qkv[(long)(qb * 128 + row) * 2304 + qc + cq];
  }
  asm volatile("s_waitcnt vmcnt(0) lgkmcnt(0)" ::: "memory");
  __builtin_amdgcn_s_barrier();
  __builtin_amdgcn_sched_barrier(0);

  s16x8 qf[2][2];
#pragma unroll
  for (int m = 0; m < 2; ++m)
#pragma unroll
    for (int ks = 0; ks < 2; ++ks) {
      int row = wave * 32 + m * 16 + lr;
      s16x8 v = *(const s16x8*)&Ps[row * 72 + ks * 32 + lg * 8];
#pragma unroll
      for (int e = 0; e < 8; ++e) {
        __bf16 b = (__bf16)(bf2f(v[e]) * QSCALE);
        v[e] = (short)__builtin_bit_cast(unsigned short, b);
      }
      qf[m][ks] = v;
    }

  float l_part[2] = {0.f, 0.f};
  f32x4 oacc[2][4] = {};

  int cur = 0;
  for (int it = 0; it < 32; ++it) {
    if (it < 31) STAGE(cur ^ 1, it + 1);

    f32x4 sacc[2][4] = {};
#pragma unroll
    for (int ks = 0; ks < 2; ++ks) {
      s16x8 kf[4];
#pragma unroll
      for (int n = 0; n < 4; ++n) {
        int row = n * 16 + lr;
        int chk = (ks * 4 + lg) ^ (lr & 7);
        kf[n] = *(const s16x8*)&Kt[cur][row * 64 + chk * 8];
      }
      __builtin_amdgcn_s_setprio(1);
#pragma unroll
      for (int m = 0; m < 2; ++m)
#pragma unroll
        for (int n = 0; n < 4; ++n)
          sacc[m][n] = mfma16(kf[n], qf[m][ks], sacc[m][n]);
      __builtin_amdgcn_s_setprio(0);
    }
#pragma unroll
    for (int m = 0; m < 2; ++m) {
      const int prow = wave * 32 + m * 16 + lr;
      float rs = 0.f;
#pragma unroll
      for (int n = 0; n < 4; ++n) {
        float p0 = __builtin_amdgcn_exp2f(sacc[m][n][0]);
        float p1 = __builtin_amdgcn_exp2f(sacc[m][n][1]);
        float p2 = __builtin_amdgcn_exp2f(sacc[m][n][2]);
        float p3 = __builtin_amdgcn_exp2f(sacc[m][n][3]);
        rs += (p0 + p1) + (p2 + p3);
        bf16x4 pk;
        pk[0] = (__bf16)p0; pk[1] = (__bf16)p1;
        pk[2] = (__bf16)p2; pk[3] = (__bf16)p3;
        *(bf16x4*)&Ps[prow * 72 + n * 16 + lg * 4] = pk;
      }
      l_part[m] += rs;
    }
#pragma unroll
    for (int ks = 0; ks < 2; ++ks) {
      s16x8 pf[2], vf[4];
#pragma unroll
      for (int m = 0; m < 2; ++m) {
        int row = wave * 32 + m * 16 + lr;
        pf[m] = *(const s16x8*)&Ps[row * 72 + ks * 32 + lg * 8];
      }
#pragma unroll
      for (int n = 0; n < 4; ++n) {
        int row = n * 16 + lr;
        int chk = (ks * 4 + lg) ^ (lr & 7);
        vf[n] = *(const s16x8*)&Vs[cur][row * 64 + chk * 8];
      }
      __builtin_amdgcn_s_setprio(1);
#pragma unroll
      for (int m = 0; m < 2; ++m)
#pragma unroll
        for (int n = 0; n < 4; ++n)
          oacc[m][n] = mfma16(pf[m], vf[n], oacc[m][n]);
      __builtin_amdgcn_s_setprio(0);
    }
    if (it < 31) {
      asm volatile("s_waitcnt vmcnt(0)" ::: "memory");
      __builtin_amdgcn_s_barrier();
      __builtin_amdgcn_sched_barrier(0);
      cur ^= 1;
    }
  }

  const long pbase = ((long)(h * 32 + qb) * 2 + sp) * 128;
#pragma unroll
  for (int m = 0; m < 2; ++m) {
    float l = l_part[m];
    l += __shfl_xor(l, 16);
    l += __shfl_xor(l, 32);
    if (lane < 16) Lpart[pbase + wave * 32 + m * 16 + lr] = l;
  }
#pragma unroll
  for (int m = 0; m < 2; ++m)
#pragma unroll
    for (int n = 0; n < 4; ++n)
#pragma unroll
      for (int j = 0; j < 4; ++j) {
        int row = wave * 32 + m * 16 + lg * 4 + j;
        Opart[(pbase + row) * 64 + n * 16 + lr] = f2bf(oacc[m][n][j]);
      }
}

// ---------------- combine split partials (bf16 O) -> ctx (bf16) ----------------
__global__ __launch_bounds__(256) void combine_kernel(const short* __restrict__ Opart,
                                                      const float* __restrict__ Lpart,
                                                      short* __restrict__ ctx) {
  const int row = blockIdx.x;
  const int col = blockIdx.y * 256 + threadIdx.x;
  const int h = col >> 6, c = col & 63;
  const int qb = row >> 7, r = row & 127;
  const long p0 = ((long)(h * 32 + qb) * 2) * 128 + r;
  const long p1 = p0 + 128;
  float l = Lpart[p0] + Lpart[p1];
  float o = bf2f(Opart[p0 * 64 + c]) + bf2f(Opart[p1 * 64 + c]);
  ctx[(long)row * 768 + col] = f2bf(o / l);
}

// ---------------- residual(f32 a + 2 bf16 partials) + LayerNorm ----------------
__global__ __launch_bounds__(256) void ln_kernel(const float* __restrict__ a,
                                                 const short* __restrict__ b,
                                                 const short* __restrict__ c,
                                                 const float* __restrict__ g,
                                                 const float* __restrict__ be,
                                                 float* __restrict__ of,
                                                 short* __restrict__ ob) {
  const int row = blockIdx.x;
  const int tid = threadIdx.x;
  const long base = (long)row * 768;
  float v[3];
  float s1 = 0.f, s2 = 0.f;
#pragma unroll
  for (int kk = 0; kk < 3; ++kk) {
    int i = tid + kk * 256;
    float x = a[base + i] + bf2f(b[base + i]) + bf2f(c[base + i]);
    v[kk] = x;
    s1 += x;
    s2 += x * x;
  }
#pragma unroll
  for (int off = 1; off < 64; off <<= 1) {
    s1 += __shfl_xor(s1, off);
    s2 += __shfl_xor(s2, off);
  }
  __shared__ float ws1[4], ws2[4];
  int wave = tid >> 6;
  if ((tid & 63) == 0) { ws1[wave] = s1; ws2[wave] = s2; }
  __syncthreads();
  s1 = ws1[0] + ws1[1] + ws1[2] + ws1[3];
  s2 = ws2[0] + ws2[1] + ws2[2] + ws2[3];
  float mean = s1 * (1.f / 768.f);
  float var = s2 * (1.f / 768.f) - mean * mean;
  float rstd = rsqrtf(var + 1e-5f);
#pragma unroll
  for (int kk = 0; kk < 3; ++kk) {
    int i = tid + kk * 256;
    float o = (v[kk] - mean) * rstd * g[i] + be[i];
    if (of) of[base + i] = o;
    if (ob) ob[base + i] = f2bf(o);
  }
}

extern "C" void kernel_launch(void* const* d_in, const int* in_sizes, int n_in,
                              void* d_out, int out_size, void* d_ws, size_t ws_size,
                              hipStream_t stream) {
  const float* x   = (const float*)d_in[0];
  const float* Wq  = (const float*)d_in[1];
  const float* bq  = (const float*)d_in[2];
  const float* Wk  = (const float*)d_in[3];
  const float* bk  = (const float*)d_in[4];
  const float* Wv  = (const float*)d_in[5];
  const float* bv  = (const float*)d_in[6];
  const float* Wo  = (const float*)d_in[7];
  const float* bo  = (const float*)d_in[8];
  const float* g1  = (const float*)d_in[9];
  const float* be1 = (const float*)d_in[10];
  const float* W1  = (const float*)d_in[11];
  const float* b1  = (const float*)d_in[12];
  const float* W2  = (const float*)d_in[13];
  const float* b2  = (const float*)d_in[14];
  const float* g2  = (const float*)d_in[15];
  const float* be2 = (const float*)d_in[16];

  char* ws = (char*)d_ws;
  size_t off = 0;
  auto alloc = [&](size_t bytes) {
    char* p = ws + off;
    off += (bytes + 255) & ~(size_t)255;
    return p;
  };
  short* xb     = (short*)alloc(4096ul * 768 * 2);
  short* wqkv_t = (short*)alloc(2304ul * 768 * 2);
  short* wo_t   = (short*)alloc(768ul * 768 * 2);
  short* w1_t   = (short*)alloc(3072ul * 768 * 2);
  short* w2_t   = (short*)alloc(768ul * 3072 * 2);
  float* bqkv   = (float*)alloc(2304ul * 4);
  short* qkv    = (short*)alloc(4096ul * 2304 * 2);   // 18.87 MB
  short* vt     = (short*)alloc(768ul * 4096 * 2);    // 6.29 MB
  short* ctx    = (short*)alloc(4096ul * 768 * 2);
  float* attn_o = (float*)alloc(4096ul * 768 * 4);
  short* h_b    = (short*)alloc(4096ul * 768 * 2);
  float* h_f    = (float*)alloc(4096ul * 768 * 4);
  short* f1     = (short*)alloc(4096ul * 3072 * 2);
  // Aliases (lifetime-disjoint):
  short* Opart  = (short*)f1;      // 12.6 MB bf16; f1 written after combine
  float* Lpart  = (float*)attn_o;  // 0.4 MB; dead before ln1 partials exist
  short* attn_pb = (short*)qkv;    // 2 x 6.3 MB bf16 partials over qkv (dead post-flash)
  short* ffn_pb  = (short*)qkv;    // same region; attn_pb dead after ln1

  prep_kernel<<<8457, 256, 0, stream>>>(x, xb, bq, bk, bv, bqkv,
                                        Wq, Wk, Wv, Wo, W1, W2,
                                        wqkv_t, wo_t, w1_t, w2_t);
  gemm_kernel<0><<<dim3(32, 18), 256, 0, stream>>>(xb, wqkv_t, bqkv, qkv, vt,
                                                   4096, 2304, 768, 768);
  flash_kernel<<<dim3(32, 12, 2), 256, 0, stream>>>(qkv, vt, Opart, Lpart);
  combine_kernel<<<dim3(4096, 3), 256, 0, stream>>>(Opart, Lpart, ctx);
  gemm_kernel<3><<<dim3(32, 6, 2), 256, 0, stream>>>(ctx, wo_t, bo, attn_pb, nullptr,
                                                     4096, 768, 768, 384);
  ln_kernel<<<4096, 256, 0, stream>>>(x, attn_pb, attn_pb + 4096ul * 768, g1, be1,
                                      h_f, h_b);
  gemm_kernel<2><<<dim3(32, 24), 256, 0, stream>>>(h_b, w1_t, b1, f1, nullptr,
                                                   4096, 3072, 768, 768);
  gemm_kernel<3><<<dim3(32, 6, 2), 256, 0, stream>>>(f1, w2_t, b2, ffn_pb, nullptr,
                                                     4096, 768, 3072, 1536);
  ln_kernel<<<4096, 256, 0, stream>>>(h_f, ffn_pb, ffn_pb + 4096ul * 768, g2, be2,
                                      (float*)d_out, nullptr);
}

// Round 14
// 213.594 us; speedup vs baseline: 1.0441x; 1.0441x over previous
//
#include <hip/hip_runtime.h>
#include <hip/hip_bf16.h>

typedef __attribute__((ext_vector_type(8))) short s16x8;
typedef __attribute__((ext_vector_type(4))) short s16x4;
typedef __attribute__((ext_vector_type(4))) int   i32x4;
typedef __attribute__((ext_vector_type(4))) float f32x4;
typedef __attribute__((ext_vector_type(8))) __bf16 bf16x8;
typedef __attribute__((ext_vector_type(4))) __bf16 bf16x4;

__device__ __forceinline__ short f2bf(float f) {
  unsigned u = __builtin_bit_cast(unsigned, f);
  u = (u + 0x7FFFu + ((u >> 16) & 1u)) >> 16;
  return (short)u;
}
__device__ __forceinline__ float bf2f(short s) {
  unsigned u = ((unsigned)(unsigned short)s) << 16;
  return __builtin_bit_cast(float, u);
}
__device__ __forceinline__ f32x4 mfma16(s16x8 a, s16x8 b, f32x4 c) {
  return __builtin_amdgcn_mfma_f32_16x16x32_bf16(
      __builtin_bit_cast(bf16x8, a), __builtin_bit_cast(bf16x8, b), c, 0, 0, 0);
}
__device__ __forceinline__ void gload16(const void* g, void* l) {
  __builtin_amdgcn_global_load_lds(
      (const __attribute__((address_space(1))) void*)g,
      (__attribute__((address_space(3))) void*)l, 16, 0, 0);
}

// ---------------- merged prep: convert x, bias concat, 6x weight conv+transpose ----
__global__ __launch_bounds__(256) void prep_kernel(
    const float* __restrict__ x, short* __restrict__ xb,
    const float* __restrict__ bq, const float* __restrict__ bk,
    const float* __restrict__ bv, float* __restrict__ bqkv,
    const float* __restrict__ Wq, const float* __restrict__ Wk,
    const float* __restrict__ Wv, const float* __restrict__ Wo,
    const float* __restrict__ W1, const float* __restrict__ W2,
    short* __restrict__ wqkv_t, short* __restrict__ wo_t,
    short* __restrict__ w1_t, short* __restrict__ w2_t) {
  __shared__ float t[32][33];
  const int b = blockIdx.x, tid = threadIdx.x;
  if (b < 1536) {
    int i = b * 256 + tid;
    float4 v0 = ((const float4*)x)[i * 2];
    float4 v1 = ((const float4*)x)[i * 2 + 1];
    s16x8 o;
    o[0] = f2bf(v0.x); o[1] = f2bf(v0.y); o[2] = f2bf(v0.z); o[3] = f2bf(v0.w);
    o[4] = f2bf(v1.x); o[5] = f2bf(v1.y); o[6] = f2bf(v1.z); o[7] = f2bf(v1.w);
    *(s16x8*)&xb[i * 8] = o;
    return;
  }
  if (b < 1545) {
    int i = (b - 1536) * 256 + tid;
    if (i < 2304) bqkv[i] = i < 768 ? bq[i] : (i < 1536 ? bk[i - 768] : bv[i - 1536]);
    return;
  }
  const float* src; short* dst; int K, N, bx, by;
  if (b < 3849) {
    int t4 = b - 1545, wi = t4 / 576, r = t4 % 576;
    bx = r % 24; by = r / 24; K = 768; N = 768;
    src = wi == 0 ? Wq : wi == 1 ? Wk : wi == 2 ? Wv : Wo;
    dst = wi == 0 ? wqkv_t : wi == 1 ? wqkv_t + 768 * 768
        : wi == 2 ? wqkv_t + 2 * 768 * 768 : wo_t;
  } else if (b < 6153) {
    int r = b - 3849; bx = r % 96; by = r / 96; K = 768; N = 3072; src = W1; dst = w1_t;
  } else {
    int r = b - 6153; bx = r % 24; by = r / 24; K = 3072; N = 768; src = W2; dst = w2_t;
  }
  int n0 = bx * 32, k0 = by * 32;
  int tx = tid & 31, ty = tid >> 5;
#pragma unroll
  for (int r = 0; r < 4; ++r) t[ty + r * 8][tx] = src[(long)(k0 + ty + r * 8) * N + n0 + tx];
  __syncthreads();
#pragma unroll
  for (int r = 0; r < 4; ++r)
    dst[(long)(n0 + ty + r * 8) * K + k0 + tx] = f2bf(t[tx][ty + r * 8]);
}

// ---------------- GEMM (3-stage pipeline, round-11 proven schedule) ----------------
// C = A[M][Kfull](cols koff..) @ Bt^T + bias
// OUT_MODE: 0 = bf16 out, 1 = f32 out (split-K capable), 2 = bf16 out with GELU
template <int OUT_MODE>
__global__ __launch_bounds__(256) void gemm_kernel(const short* __restrict__ A,
                                                   const short* __restrict__ Bt,
                                                   const float* __restrict__ bias,
                                                   void* __restrict__ Cout,
                                                   short* __restrict__ vtout,
                                                   int M, int N, int Kfull, int Ksub) {
  __shared__ short As[3][64 * 64];
  __shared__ short Bs[3][64 * 64];
  const int tid = threadIdx.x;
  const int wave = tid >> 6, lane = tid & 63;
  const int lr = lane & 15, lg = lane >> 4;
  const int wm = wave >> 1, wn = wave & 1;
  const int bm = blockIdx.x, bn = blockIdx.y;
  const long koff = (long)blockIdx.z * Ksub;

  f32x4 acc[4][4] = {};

  const short* Ab = A + (long)bm * 128 * Kfull + koff;
  const short* Bb = Bt + (long)bn * 128 * Kfull + koff;

  int sj[2], sr[2], skc[2];
#pragma unroll
  for (int rnd = 0; rnd < 2; ++rnd) {
    int c = tid + rnd * 256;
    int j = c >> 3, c7 = c & 7;
    int u = c7 ^ (j & 7);
    sj[rnd] = c;
    sr[rnd] = j + ((u >> 2) << 6);
    skc[rnd] = (u & 3) * 8;
  }

  auto STAGE = [&](int buf, int k0) {
#pragma unroll
    for (int rnd = 0; rnd < 2; ++rnd) {
      gload16(Ab + (long)sr[rnd] * Kfull + k0 + skc[rnd], &As[buf][sj[rnd] * 8]);
      gload16(Bb + (long)sr[rnd] * Kfull + k0 + skc[rnd], &Bs[buf][sj[rnd] * 8]);
    }
  };
  auto COMPUTE = [&](int buf) {
    s16x8 af[4], bfr[4];
#pragma unroll
    for (int m = 0; m < 4; ++m) {
      int j = m * 16 + lr;
      int c7 = ((wm << 2) | lg) ^ (lr & 7);
      af[m] = *(const s16x8*)&As[buf][j * 64 + c7 * 8];
    }
#pragma unroll
    for (int n = 0; n < 4; ++n) {
      int j = n * 16 + lr;
      int c7 = ((wn << 2) | lg) ^ (lr & 7);
      bfr[n] = *(const s16x8*)&Bs[buf][j * 64 + c7 * 8];
    }
#pragma unroll
    for (int m = 0; m < 4; ++m)
#pragma unroll
      for (int n = 0; n < 4; ++n)
        acc[m][n] = mfma16(af[m], bfr[n], acc[m][n]);
  };

  const int nt = Ksub >> 5;  // >= 12 for all our shapes
  STAGE(0, 0);
  STAGE(1, 32);
  int cur = 0;
  for (int t = 0; t < nt - 2; ++t) {
    int nb = cur + 2; if (nb >= 3) nb -= 3;
    STAGE(nb, (t + 2) * 32);                 // tile t+2 in flight
    asm volatile("s_waitcnt vmcnt(8)" ::: "memory");  // tile t landed
    __builtin_amdgcn_s_barrier();
    __builtin_amdgcn_sched_barrier(0);
    COMPUTE(cur);
    __builtin_amdgcn_s_barrier();            // all waves done reading buf[cur]
    cur = (cur == 2) ? 0 : cur + 1;
  }
  asm volatile("s_waitcnt vmcnt(4)" ::: "memory");    // tile nt-2 landed
  __builtin_amdgcn_s_barrier();
  __builtin_amdgcn_sched_barrier(0);
  COMPUTE(cur);
  __builtin_amdgcn_s_barrier();
  cur = (cur == 2) ? 0 : cur + 1;
  asm volatile("s_waitcnt vmcnt(0)" ::: "memory");    // tile nt-1 landed
  __builtin_amdgcn_s_barrier();
  __builtin_amdgcn_sched_barrier(0);
  COMPUTE(cur);

  const int gr0 = bm * 128 + wm * 64 + lg * 4;
  const int gc0 = bn * 128 + wn * 64 + lr;
  if (OUT_MODE == 0 && vtout != nullptr && bn >= 12) {
#pragma unroll
    for (int n = 0; n < 4; ++n) {
      int col = gc0 + n * 16;
      float bb = bias[col];
#pragma unroll
      for (int m = 0; m < 4; ++m) {
        s16x4 pk;
#pragma unroll
        for (int j = 0; j < 4; ++j) pk[j] = f2bf(acc[m][n][j] + bb);
        *(s16x4*)&vtout[(long)(col - 1536) * 4096 + gr0 + m * 16] = pk;
      }
    }
    return;
  }
  float* outF = (float*)Cout + (long)blockIdx.z * M * N;
#pragma unroll
  for (int n = 0; n < 4; ++n) {
    int col = gc0 + n * 16;
    float bb = (blockIdx.z == 0) ? bias[col] : 0.f;
#pragma unroll
    for (int m = 0; m < 4; ++m) {
#pragma unroll
      for (int j = 0; j < 4; ++j) {
        int row = gr0 + m * 16 + j;
        float v = acc[m][n][j] + bb;
        if (OUT_MODE == 2) v = 0.5f * v * (1.0f + erff(v * 0.70710678118f));
        if (OUT_MODE == 1) outF[(long)row * N + col] = v;
        else ((short*)Cout)[(long)row * N + col] = f2bf(v);
      }
    }
  }
}

// ---------------- Flash attention v9 (r13 proven): gload_lds staging, bf16 Opart ----
__global__ __launch_bounds__(256) void flash_kernel(const short* __restrict__ qkv,
                                                    const short* __restrict__ vt,
                                                    short* __restrict__ Opart,
                                                    float* __restrict__ Lpart) {
  __shared__ short Kt[2][64 * 64];
  __shared__ short Vs[2][64 * 64];
  __shared__ short Ps[128 * 72];  // [q][kv] padded; also reused for Q staging
  const int tid = threadIdx.x;
  const int wave = tid >> 6, lane = tid & 63;
  const int lr = lane & 15, lg = lane >> 4;
  const int lb = blockIdx.x + 32 * blockIdx.y + 384 * blockIdx.z;
  const int nlb = (lb & 7) * 96 + (lb >> 3);
  const int qb = nlb & 31;
  const int h = (nlb >> 5) % 12;
  const int sp = nlb / 384;
  const int qc = h * 64;
  const int hc = 768 + h * 64;
  const int vr = h * 64;
  const float QSCALE = 0.125f * 1.44269504088896f;
  const int sbase = sp * 2048;

  auto STAGE = [&](int buf, int it) {
    const int s0 = sbase + it * 64;
#pragma unroll
    for (int i = 0; i < 2; ++i) {
      int c = tid + i * 256, row = c >> 3, ch = (c & 7) ^ (row & 7);
      gload16(&qkv[(long)(s0 + row) * 2304 + hc + ch * 8], &Kt[buf][c * 8]);
      gload16(&vt[(long)(vr + row) * 4096 + s0 + ch * 8], &Vs[buf][c * 8]);
    }
  };

  STAGE(0, 0);

#pragma unroll
  for (int i = 0; i < 4; ++i) {
    int c = tid + i * 256;
    int row = c >> 3, cq = (c & 7) * 8;
    *(i32x4*)&Ps[row * 72 + cq] =
        *(const i32x4*)&qkv[(long)(qb * 128 + row) * 2304 + qc + cq];
  }
  asm volatile("s_waitcnt vmcnt(0) lgkmcnt(0)" ::: "memory");
  __builtin_amdgcn_s_barrier();
  __builtin_amdgcn_sched_barrier(0);

  s16x8 qf[2][2];
#pragma unroll
  for (int m = 0; m < 2; ++m)
#pragma unroll
    for (int ks = 0; ks < 2; ++ks) {
      int row = wave * 32 + m * 16 + lr;
      s16x8 v = *(const s16x8*)&Ps[row * 72 + ks * 32 + lg * 8];
#pragma unroll
      for (int e = 0; e < 8; ++e) {
        __bf16 b = (__bf16)(bf2f(v[e]) * QSCALE);
        v[e] = (short)__builtin_bit_cast(unsigned short, b);
      }
      qf[m][ks] = v;
    }

  float l_part[2] = {0.f, 0.f};
  f32x4 oacc[2][4] = {};

  int cur = 0;
  for (int it = 0; it < 32; ++it) {
    if (it < 31) STAGE(cur ^ 1, it + 1);

    f32x4 sacc[2][4] = {};
#pragma unroll
    for (int ks = 0; ks < 2; ++ks) {
      s16x8 kf[4];
#pragma unroll
      for (int n = 0; n < 4; ++n) {
        int row = n * 16 + lr;
        int chk = (ks * 4 + lg) ^ (lr & 7);
        kf[n] = *(const s16x8*)&Kt[cur][row * 64 + chk * 8];
      }
      __builtin_amdgcn_s_setprio(1);
#pragma unroll
      for (int m = 0; m < 2; ++m)
#pragma unroll
        for (int n = 0; n < 4; ++n)
          sacc[m][n] = mfma16(kf[n], qf[m][ks], sacc[m][n]);
      __builtin_amdgcn_s_setprio(0);
    }
#pragma unroll
    for (int m = 0; m < 2; ++m) {
      const int prow = wave * 32 + m * 16 + lr;
      float rs = 0.f;
#pragma unroll
      for (int n = 0; n < 4; ++n) {
        float p0 = __builtin_amdgcn_exp2f(sacc[m][n][0]);
        float p1 = __builtin_amdgcn_exp2f(sacc[m][n][1]);
        float p2 = __builtin_amdgcn_exp2f(sacc[m][n][2]);
        float p3 = __builtin_amdgcn_exp2f(sacc[m][n][3]);
        rs += (p0 + p1) + (p2 + p3);
        bf16x4 pk;
        pk[0] = (__bf16)p0; pk[1] = (__bf16)p1;
        pk[2] = (__bf16)p2; pk[3] = (__bf16)p3;
        *(bf16x4*)&Ps[prow * 72 + n * 16 + lg * 4] = pk;
      }
      l_part[m] += rs;
    }
#pragma unroll
    for (int ks = 0; ks < 2; ++ks) {
      s16x8 pf[2], vf[4];
#pragma unroll
      for (int m = 0; m < 2; ++m) {
        int row = wave * 32 + m * 16 + lr;
        pf[m] = *(const s16x8*)&Ps[row * 72 + ks * 32 + lg * 8];
      }
#pragma unroll
      for (int n = 0; n < 4; ++n) {
        int row = n * 16 + lr;
        int chk = (ks * 4 + lg) ^ (lr & 7);
        vf[n] = *(const s16x8*)&Vs[cur][row * 64 + chk * 8];
      }
      __builtin_amdgcn_s_setprio(1);
#pragma unroll
      for (int m = 0; m < 2; ++m)
#pragma unroll
        for (int n = 0; n < 4; ++n)
          oacc[m][n] = mfma16(pf[m], vf[n], oacc[m][n]);
      __builtin_amdgcn_s_setprio(0);
    }
    if (it < 31) {
      asm volatile("s_waitcnt vmcnt(0)" ::: "memory");
      __builtin_amdgcn_s_barrier();
      __builtin_amdgcn_sched_barrier(0);
      cur ^= 1;
    }
  }

  const long pbase = ((long)(h * 32 + qb) * 2 + sp) * 128;
#pragma unroll
  for (int m = 0; m < 2; ++m) {
    float l = l_part[m];
    l += __shfl_xor(l, 16);
    l += __shfl_xor(l, 32);
    if (lane < 16) Lpart[pbase + wave * 32 + m * 16 + lr] = l;
  }
#pragma unroll
  for (int m = 0; m < 2; ++m)
#pragma unroll
    for (int n = 0; n < 4; ++n)
#pragma unroll
      for (int j = 0; j < 4; ++j) {
        int row = wave * 32 + m * 16 + lg * 4 + j;
        Opart[(pbase + row) * 64 + n * 16 + lr] = f2bf(oacc[m][n][j]);
      }
}

// ---------------- combine split partials (bf16 O) -> ctx (bf16) ----------------
__global__ __launch_bounds__(256) void combine_kernel(const short* __restrict__ Opart,
                                                      const float* __restrict__ Lpart,
                                                      short* __restrict__ ctx) {
  const int row = blockIdx.x;
  const int col = blockIdx.y * 256 + threadIdx.x;
  const int h = col >> 6, c = col & 63;
  const int qb = row >> 7, r = row & 127;
  const long p0 = ((long)(h * 32 + qb) * 2) * 128 + r;
  const long p1 = p0 + 128;
  float l = Lpart[p0] + Lpart[p1];
  float o = bf2f(Opart[p0 * 64 + c]) + bf2f(Opart[p1 * 64 + c]);
  ctx[(long)row * 768 + col] = f2bf(o / l);
}

// ---------------- residual(a + 2 f32 partials) + LayerNorm ----------------
// AF: 1 = a is f32, 0 = a is bf16.  OF: 1 = write f32 out, 0 = write bf16 out.
template <int AF, int OF>
__global__ __launch_bounds__(256) void ln_kernel(const void* __restrict__ a_,
                                                 const float* __restrict__ b,
                                                 const float* __restrict__ c,
                                                 const float* __restrict__ g,
                                                 const float* __restrict__ be,
                                                 void* __restrict__ out_) {
  const int row = blockIdx.x;
  const int tid = threadIdx.x;
  const long base = (long)row * 768;
  float v[3];
  float s1 = 0.f, s2 = 0.f;
#pragma unroll
  for (int kk = 0; kk < 3; ++kk) {
    int i = tid + kk * 256;
    float av = AF ? ((const float*)a_)[base + i] : bf2f(((const short*)a_)[base + i]);
    float x = av + b[base + i] + c[base + i];
    v[kk] = x;
    s1 += x;
    s2 += x * x;
  }
#pragma unroll
  for (int off = 1; off < 64; off <<= 1) {
    s1 += __shfl_xor(s1, off);
    s2 += __shfl_xor(s2, off);
  }
  __shared__ float ws1[4], ws2[4];
  int wave = tid >> 6;
  if ((tid & 63) == 0) { ws1[wave] = s1; ws2[wave] = s2; }
  __syncthreads();
  s1 = ws1[0] + ws1[1] + ws1[2] + ws1[3];
  s2 = ws2[0] + ws2[1] + ws2[2] + ws2[3];
  float mean = s1 * (1.f / 768.f);
  float var = s2 * (1.f / 768.f) - mean * mean;
  float rstd = rsqrtf(var + 1e-5f);
#pragma unroll
  for (int kk = 0; kk < 3; ++kk) {
    int i = tid + kk * 256;
    float o = (v[kk] - mean) * rstd * g[i] + be[i];
    if (OF) ((float*)out_)[base + i] = o;
    else    ((short*)out_)[base + i] = f2bf(o);
  }
}

extern "C" void kernel_launch(void* const* d_in, const int* in_sizes, int n_in,
                              void* d_out, int out_size, void* d_ws, size_t ws_size,
                              hipStream_t stream) {
  const float* x   = (const float*)d_in[0];
  const float* Wq  = (const float*)d_in[1];
  const float* bq  = (const float*)d_in[2];
  const float* Wk  = (const float*)d_in[3];
  const float* bk  = (const float*)d_in[4];
  const float* Wv  = (const float*)d_in[5];
  const float* bv  = (const float*)d_in[6];
  const float* Wo  = (const float*)d_in[7];
  const float* bo  = (const float*)d_in[8];
  const float* g1  = (const float*)d_in[9];
  const float* be1 = (const float*)d_in[10];
  const float* W1  = (const float*)d_in[11];
  const float* b1  = (const float*)d_in[12];
  const float* W2  = (const float*)d_in[13];
  const float* b2  = (const float*)d_in[14];
  const float* g2  = (const float*)d_in[15];
  const float* be2 = (const float*)d_in[16];

  char* ws = (char*)d_ws;
  size_t off = 0;
  auto alloc = [&](size_t bytes) {
    char* p = ws + off;
    off += (bytes + 255) & ~(size_t)255;
    return p;
  };
  short* xb     = (short*)alloc(4096ul * 768 * 2);
  short* wqkv_t = (short*)alloc(2304ul * 768 * 2);
  short* wo_t   = (short*)alloc(768ul * 768 * 2);
  short* w1_t   = (short*)alloc(3072ul * 768 * 2);
  short* w2_t   = (short*)alloc(768ul * 3072 * 2);
  float* bqkv   = (float*)alloc(2304ul * 4);
  short* qkv    = (short*)alloc(4096ul * 2304 * 2);   // 18.87 MB
  short* vt     = (short*)alloc(768ul * 4096 * 2);    // 6.29 MB (contiguous after qkv)
  short* ctx    = (short*)alloc(4096ul * 768 * 2);
  float* attn_o = (float*)alloc(4096ul * 768 * 4);
  short* h_b    = (short*)alloc(4096ul * 768 * 2);
  float* h_f    = (float*)alloc(4096ul * 768 * 4);    // (unused; layout kept)
  short* f1     = (short*)alloc(4096ul * 3072 * 2);
  // Aliases (lifetime-disjoint):
  short* Opart  = (short*)f1;      // 12.6 MB bf16; f1 written after combine
  float* Lpart  = (float*)attn_o;  // 0.4 MB; dead before ln1 partials exist
  float* attn_p = (float*)qkv;     // 2 x 12.58 MB f32 over qkv+vt (dead post-flash)
  float* ffn_p  = (float*)qkv;     // same region; attn_p dead after ln1

  prep_kernel<<<8457, 256, 0, stream>>>(x, xb, bq, bk, bv, bqkv,
                                        Wq, Wk, Wv, Wo, W1, W2,
                                        wqkv_t, wo_t, w1_t, w2_t);
  gemm_kernel<0><<<dim3(32, 18), 256, 0, stream>>>(xb, wqkv_t, bqkv, qkv, vt,
                                                   4096, 2304, 768, 768);
  flash_kernel<<<dim3(32, 12, 2), 256, 0, stream>>>(qkv, vt, Opart, Lpart);
  combine_kernel<<<dim3(4096, 3), 256, 0, stream>>>(Opart, Lpart, ctx);
  gemm_kernel<1><<<dim3(32, 6, 2), 256, 0, stream>>>(ctx, wo_t, bo, attn_p, nullptr,
                                                     4096, 768, 768, 384);
  ln_kernel<1, 0><<<4096, 256, 0, stream>>>(x, attn_p, attn_p + 4096ul * 768,
                                            g1, be1, h_b);
  gemm_kernel<2><<<dim3(32, 24), 256, 0, stream>>>(h_b, w1_t, b1, f1, nullptr,
                                                   4096, 3072, 768, 768);
  gemm_kernel<1><<<dim3(32, 6, 2), 256, 0, stream>>>(f1, w2_t, b2, ffn_p, nullptr,
                                                     4096, 768, 3072, 1536);
  ln_kernel<0, 1><<<4096, 256, 0, stream>>>(h_b, ffn_p, ffn_p + 4096ul * 768,
                                            g2, be2, (float*)d_out);
}